// Round 3
// baseline (21.972 us; speedup 1.0000x reference)
//
#include <hip/hip_runtime.h>
#include <cstddef>

// FTRL-FM forward, MI355X. B=4096, K=50, F=1e6, M=32.
// One 256-thread block per TWO samples (b0 = blockIdx.x, b1 = b0 + gridDim.x).
// Thread layout: wave = tid>>6, lane = tid&63, m4 = lane&7 (float4 within the
// 32-float row), g = wave*8 + (lane>>3) in [0,32) = feature slot; each thread
// also handles slot g+32 (predicated). All 8 row gathers (2 samples x {z2,n2}
// x 2 slots) are issued back-to-back before any use to maximize MLP.

namespace {
constexpr int KF = 50;
constexpr int MF = 32;

__device__ __forceinline__ float ftrl_w(float z, float n, float l1, float l2,
                                        float ss /*sign scale*/) {
  // alpha = 0.1 (both orders), beta = 1.0 -> denom = (1+sqrt(n))/0.1 + l2
  float sgn = (z >= 0.f) ? 1.f : -1.f;
  float denom = (1.0f + sqrtf(n)) * 10.0f + l2;
  float w = (sgn * ss - z) / denom;
  return (fabsf(z) <= l1) ? 0.f : w;
}
} // namespace

__global__ __launch_bounds__(256) void ftrl_fm_kernel(
    const int* __restrict__ x_idx,
    const float* __restrict__ z1t, const float* __restrict__ n1t,
    const float* __restrict__ z2t, const float* __restrict__ n2t,
    float* __restrict__ out, int B) {
  const int tid = threadIdx.x;
  const int wave = tid >> 6;
  const int lane = tid & 63;
  const int m4 = lane & 7;
  const int g = wave * 8 + (lane >> 3);   // [0,32)
  const int k1 = g + 32;
  const bool act1 = (k1 < KF);
  const float actf = act1 ? 1.f : 0.f;
  const int kc = act1 ? k1 : g;           // in-bounds; duplicates g when inactive

  const int b0 = blockIdx.x;
  const int b1 = b0 + gridDim.x;
  const bool has1 = (b1 < B);

  const int* __restrict__ row0 = x_idx + (size_t)b0 * KF;
  const int* __restrict__ row1 = x_idx + (size_t)(has1 ? b1 : b0) * KF;

  // ---- all index loads first (x_idx rows are L1/L2-resident) ----
  const int a0 = row0[g];
  const int a1 = row0[kc];
  const int c0 = row1[g];
  const int c1 = row1[kc];
  const int tfeat = (tid < KF) ? tid : 0;
  const int i1a = row0[tfeat];
  const int i1b = row1[tfeat];

  // ---- all 8 row gathers issued before any use ----
  const float4* __restrict__ z2v = (const float4*)z2t;
  const float4* __restrict__ n2v = (const float4*)n2t;
  const float4 Az0 = z2v[a0 * 8 + m4];
  const float4 An0 = n2v[a0 * 8 + m4];
  const float4 Az1 = z2v[a1 * 8 + m4];
  const float4 An1 = n2v[a1 * 8 + m4];
  const float4 Cz0 = z2v[c0 * 8 + m4];
  const float4 Cn0 = n2v[c0 * 8 + m4];
  const float4 Cz1 = z2v[c1 * 8 + m4];
  const float4 Cn1 = n2v[c1 * 8 + m4];

  // 1st-order state (4 MB tables, cache-resident)
  const float z1a = z1t[i1a], n1a = n1t[i1a];
  const float z1b = z1t[i1b], n1b = n1t[i1b];

  __shared__ float sMem[2][4][32];
  __shared__ float pMem[2][4];

  // ================= sample 0 =================
  {
    float wx = ftrl_w(Az0.x, An0.x, 0.05f, 1.0f, 0.05f);
    float wy = ftrl_w(Az0.y, An0.y, 0.05f, 1.0f, 0.05f);
    float wz = ftrl_w(Az0.z, An0.z, 0.05f, 1.0f, 0.05f);
    float ww = ftrl_w(Az0.w, An0.w, 0.05f, 1.0f, 0.05f);
    float4 s = make_float4(wx, wy, wz, ww);
    float sumsq = wx * wx + wy * wy + wz * wz + ww * ww;
    wx = actf * ftrl_w(Az1.x, An1.x, 0.05f, 1.0f, 0.05f);
    wy = actf * ftrl_w(Az1.y, An1.y, 0.05f, 1.0f, 0.05f);
    wz = actf * ftrl_w(Az1.z, An1.z, 0.05f, 1.0f, 0.05f);
    ww = actf * ftrl_w(Az1.w, An1.w, 0.05f, 1.0f, 0.05f);
    s.x += wx; s.y += wy; s.z += wz; s.w += ww;
    sumsq += wx * wx + wy * wy + wz * wz + ww * ww;

#pragma unroll
    for (int off = 8; off < 64; off <<= 1) {
      s.x += __shfl_xor(s.x, off, 64);
      s.y += __shfl_xor(s.y, off, 64);
      s.z += __shfl_xor(s.z, off, 64);
      s.w += __shfl_xor(s.w, off, 64);
    }
    if (lane < 8) *(float4*)&sMem[0][wave][lane * 4] = s;

    float v = ((tid < KF) ? ftrl_w(z1a, n1a, 0.05f, 0.05f, 0.05f) : 0.f)
            - 0.5f * sumsq;
#pragma unroll
    for (int off = 1; off < 64; off <<= 1) v += __shfl_xor(v, off, 64);
    if (lane == 0) pMem[0][wave] = v;
  }

  // ================= sample 1 =================
  {
    float wx = ftrl_w(Cz0.x, Cn0.x, 0.05f, 1.0f, 0.05f);
    float wy = ftrl_w(Cz0.y, Cn0.y, 0.05f, 1.0f, 0.05f);
    float wz = ftrl_w(Cz0.z, Cn0.z, 0.05f, 1.0f, 0.05f);
    float ww = ftrl_w(Cz0.w, Cn0.w, 0.05f, 1.0f, 0.05f);
    float4 s = make_float4(wx, wy, wz, ww);
    float sumsq = wx * wx + wy * wy + wz * wz + ww * ww;
    wx = actf * ftrl_w(Cz1.x, Cn1.x, 0.05f, 1.0f, 0.05f);
    wy = actf * ftrl_w(Cz1.y, Cn1.y, 0.05f, 1.0f, 0.05f);
    wz = actf * ftrl_w(Cz1.z, Cn1.z, 0.05f, 1.0f, 0.05f);
    ww = actf * ftrl_w(Cz1.w, Cn1.w, 0.05f, 1.0f, 0.05f);
    s.x += wx; s.y += wy; s.z += wz; s.w += ww;
    sumsq += wx * wx + wy * wy + wz * wz + ww * ww;

#pragma unroll
    for (int off = 8; off < 64; off <<= 1) {
      s.x += __shfl_xor(s.x, off, 64);
      s.y += __shfl_xor(s.y, off, 64);
      s.z += __shfl_xor(s.z, off, 64);
      s.w += __shfl_xor(s.w, off, 64);
    }
    if (lane < 8) *(float4*)&sMem[1][wave][lane * 4] = s;

    float v = ((tid < KF) ? ftrl_w(z1b, n1b, 0.05f, 0.05f, 0.05f) : 0.f)
            - 0.5f * sumsq;
#pragma unroll
    for (int off = 1; off < 64; off <<= 1) v += __shfl_xor(v, off, 64);
    if (lane == 0) pMem[1][wave] = v;
  }

  __syncthreads();

  // ---- finalize: wave 0 -> sample 0, wave 1 -> sample 1, lanes parallel ----
  if (wave < 2) {
    const int sb = wave;
    float sm = 0.f;
    if (lane < 32)
      sm = sMem[sb][0][lane] + sMem[sb][1][lane] + sMem[sb][2][lane] + sMem[sb][3][lane];
    float sq = sm * sm;
#pragma unroll
    for (int off = 1; off < 32; off <<= 1) sq += __shfl_xor(sq, off, 64);
    if (lane == 0) {
      const float acc = pMem[sb][0] + pMem[sb][1] + pMem[sb][2] + pMem[sb][3];
      if (sb == 0) out[b0] = acc + 0.5f * sq;
      else if (has1) out[b1] = acc + 0.5f * sq;
    }
  }
}

extern "C" void kernel_launch(void* const* d_in, const int* in_sizes, int n_in,
                              void* d_out, int out_size, void* d_ws, size_t ws_size,
                              hipStream_t stream) {
  const int*   x_idx = (const int*)d_in[0];
  const float* z1t   = (const float*)d_in[1];
  const float* n1t   = (const float*)d_in[2];
  const float* z2t   = (const float*)d_in[3];
  const float* n2t   = (const float*)d_in[4];
  float* out = (float*)d_out;

  const int B = out_size;            // 4096 samples
  const int grid = (B + 1) / 2;      // 2 samples per block
  ftrl_fm_kernel<<<grid, 256, 0, stream>>>(x_idx, z1t, n1t, z2t, n2t, out, B);
}